// Round 17
// baseline (266.814 us; speedup 1.0000x reference)
//
#include <hip/hip_runtime.h>
#include <hip/hip_bf16.h>

// NAM_89739046683406: per-feature tiny MLP (B=32768, F=128, H=64)
// logit(b) = bias + sum_f [ relu(relu(x[b,f]*w1[f]+b1[f]) @ w2[f] + b2[f]) . w3[f] + b3[f] ]
// out = [1-sigmoid, sigmoid]
//
// R17 = R16 (proven: LB(256,3)/VGPR76/no-spill, grid 2048, plain stores,
// WRITE 4MB, FETCH 12.8MB) with three VALU shaves, structure untouched:
//   1. b2 fed directly as MFMA C operand (kills 64 acc-init movs/chunk)
//   2. v_pk_fma_f32 / v_pk_max_f32 via __builtin_elementwise_* on float2
//      vectors for h1 gen and the relu.w3 epilogue (-128 instr/chunk)
//   3. direct per-bt x loads (VMEM broadcast, prefetched) instead of
//      gather + 4 __shfl (kills the per-chunk lgkm wait chain)

#define B_SZ 32768
#define F_SZ 128
#define H_SZ 64

typedef short short8 __attribute__((ext_vector_type(8)));   // bf16 x8
typedef float floatx4 __attribute__((ext_vector_type(4)));  // fp32 x4 acc
typedef float float2v __attribute__((ext_vector_type(2)));  // fp32 x2 (pk ops)

// round-half-up bf16 pair-pack (proven form)
__device__ __forceinline__ unsigned pkbf(float lo, float hi) {
    unsigned ua = __float_as_uint(lo) + 0x8000u;
    unsigned ub = __float_as_uint(hi) + 0x8000u;
    return (ua >> 16) | (ub & 0xFFFF0000u);
}

// ws layout (bytes): [0, 1MB) w2bf fragment table; [1MB, 5MB) part[32][32768]
#define WS_PART_SHORTS 524288

// ---- prep: pack w2 -> A-fragment order (grid-strided, uniform, 256 blocks)
// fragment layout: per f, unit idx = c*64+lane (c = gt*2+ks):
//   value = w2[f][k=(c&1)*32+(lane>>4)*8+j][g=(c>>1)*16+(lane&15)], j=0..7
__global__ __launch_bounds__(256)
void nam_prep(const float* __restrict__ w2, unsigned short* __restrict__ ws)
{
    int unit = blockIdx.x * 256 + threadIdx.x;   // 0..65535
    int f    = unit >> 9;             // 0..127
    int idx  = unit & 511;
    int c    = idx >> 6;
    int lane = idx & 63;
    int g    = (c >> 1) * 16 + (lane & 15);
    int k0   = (c & 1) * 32 + (lane >> 4) * 8;
    const float* w2f = w2 + (size_t)f * 4096;
    unsigned o0 = pkbf(w2f[(k0 + 0) * 64 + g], w2f[(k0 + 1) * 64 + g]);
    unsigned o1 = pkbf(w2f[(k0 + 2) * 64 + g], w2f[(k0 + 3) * 64 + g]);
    unsigned o2 = pkbf(w2f[(k0 + 4) * 64 + g], w2f[(k0 + 5) * 64 + g]);
    unsigned o3 = pkbf(w2f[(k0 + 6) * 64 + g], w2f[(k0 + 7) * 64 + g]);
    *(uint4*)((unsigned*)ws + ((size_t)f * 512 + idx) * 4) =
        make_uint4(o0, o1, o2, o3);
}

// ---- main: block = 4 waves; wave wv owns feature f = (bx>>6)*4+wv,
//      rows [rg*512, rg*512+512), rg = bx&63. 8 chunks of 64 rows.
//      Output: part[gf][rb..rb+512) plain store (sole writer).
__global__ __launch_bounds__(256, 3)
void nam_main(const float* __restrict__ x,
              const float* __restrict__ w1, const float* __restrict__ b1,
              const float* __restrict__ b2, const float* __restrict__ w3,
              const float* __restrict__ b3,
              const unsigned short* __restrict__ ws,
              float* __restrict__ part)
{
    __shared__ float partial[4][512];    // 8KB

    const int tid  = threadIdx.x;
    const int lane = tid & 63;
    const int wv   = tid >> 6;           // 0..3
    const int l15  = lane & 15;
    const int quad = lane >> 4;
    const int rg   = blockIdx.x & 63;
    const int gf   = blockIdx.x >> 6;    // 0..31
    const int f    = gf * 4 + wv;
    const int rb   = rg * 512;

    // ---- per-wave resident tables ----
    const short8* wp = (const short8*)ws + (size_t)f * 512 + lane;
    short8 wfrag[4][2];
    #pragma unroll
    for (int gt = 0; gt < 4; ++gt)
        #pragma unroll
        for (int ks = 0; ks < 2; ++ks)
            wfrag[gt][ks] = wp[(gt * 2 + ks) * 64];

    // w1/b1 fp32 as float2 pairs: k = ks*32 + quad*8 + 2t{,+1}
    float2v wk2[2][4], bk2[2][4];
    #pragma unroll
    for (int ks = 0; ks < 2; ++ks) {
        const float4* wq = (const float4*)(w1 + f * 64 + ks * 32 + quad * 8);
        const float4* bq = (const float4*)(b1 + f * 64 + ks * 32 + quad * 8);
        float4 wa = wq[0], wb = wq[1], ba = bq[0], bb = bq[1];
        wk2[ks][0] = float2v{wa.x, wa.y}; wk2[ks][1] = float2v{wa.z, wa.w};
        wk2[ks][2] = float2v{wb.x, wb.y}; wk2[ks][3] = float2v{wb.z, wb.w};
        bk2[ks][0] = float2v{ba.x, ba.y}; bk2[ks][1] = float2v{ba.z, ba.w};
        bk2[ks][2] = float2v{bb.x, bb.y}; bk2[ks][3] = float2v{bb.z, bb.w};
    }

    // b2 as MFMA C operand; w3 as float2 pairs: g = gt*16 + quad*4 + i
    floatx4 b2c[4];
    float2v w3p[4][2];
    #pragma unroll
    for (int gt = 0; gt < 4; ++gt) {
        float4 bv = *(const float4*)(b2 + f * 64 + gt * 16 + quad * 4);
        float4 wv3 = *(const float4*)(w3 + f * 64 + gt * 16 + quad * 4);
        b2c[gt] = floatx4{bv.x, bv.y, bv.z, bv.w};
        w3p[gt][0] = float2v{wv3.x, wv3.y};
        w3p[gt][1] = float2v{wv3.z, wv3.w};
    }
    const float b3f = b3[f];
    const float2v zero2 = float2v{0.0f, 0.0f};

    // ---- 8 chunks of 64 rows; direct per-bt x loads, software-pipelined ----
    // row = rb + c*64 + bt*16 + l15 (same 16 addrs across quads -> broadcast)
    const float* xb = x + (size_t)(rb + l15) * F_SZ + f;
    float xc[4], xn[4];
    #pragma unroll
    for (int bt = 0; bt < 4; ++bt)
        xc[bt] = xb[(size_t)(bt * 16) * F_SZ];

    #pragma unroll 1
    for (int c = 0; c < 8; ++c) {
        if (c < 7) {
            #pragma unroll
            for (int bt = 0; bt < 4; ++bt)
                xn[bt] = xb[(size_t)((c + 1) * 64 + bt * 16) * F_SZ];
        }

        // h1 B-fragments: B[k=quad*8+j][n=bt*16+l15], packed-f32 math
        short8 hfrag[4][2];
        #pragma unroll
        for (int ks = 0; ks < 2; ++ks)
            #pragma unroll
            for (int bt = 0; bt < 4; ++bt) {
                float2v xbv = float2v{xc[bt], xc[bt]};
                union { short8 s8; __hip_bfloat162 h2[4]; } o;
                #pragma unroll
                for (int t = 0; t < 4; ++t) {
                    float2v h = __builtin_elementwise_fma(xbv, wk2[ks][t], bk2[ks][t]);
                    h = __builtin_elementwise_max(h, zero2);
                    o.h2[t] = __float22bfloat162_rn(make_float2(h.x, h.y));
                }
                hfrag[bt][ks] = o.s8;
            }

        // MFMA (C = b2 direct) + packed epilogue
        // D layout: g = gt*16 + quad*4 + i, n = bt*16 + l15
        float2v s2[4] = {zero2, zero2, zero2, zero2};
        #pragma unroll
        for (int gt = 0; gt < 4; ++gt)
            #pragma unroll
            for (int bt = 0; bt < 4; ++bt) {
                floatx4 acc = __builtin_amdgcn_mfma_f32_16x16x32_bf16(
                    wfrag[gt][0], hfrag[bt][0], b2c[gt], 0, 0, 0);
                acc = __builtin_amdgcn_mfma_f32_16x16x32_bf16(
                    wfrag[gt][1], hfrag[bt][1], acc, 0, 0, 0);
                float2v a01 = float2v{acc[0], acc[1]};
                float2v a23 = float2v{acc[2], acc[3]};
                s2[bt] = __builtin_elementwise_fma(
                    __builtin_elementwise_max(a01, zero2), w3p[gt][0], s2[bt]);
                s2[bt] = __builtin_elementwise_fma(
                    __builtin_elementwise_max(a23, zero2), w3p[gt][1], s2[bt]);
            }

        // horizontal + quad-reduce (row = bt*16 + l15), publish chunk rows
        #pragma unroll
        for (int bt = 0; bt < 4; ++bt) {
            float t = s2[bt].x + s2[bt].y;
            t += __shfl_xor(t, 16, 64);
            t += __shfl_xor(t, 32, 64);
            if (quad == 0)
                partial[wv][c * 64 + bt * 16 + l15] = t + b3f;
        }

        #pragma unroll
        for (int bt = 0; bt < 4; ++bt) xc[bt] = xn[bt];
    }

    __syncthreads();

    // block reduce over the 4 features -> plain coalesced store (sole writer)
    #pragma unroll
    for (int k = 0; k < 2; ++k) {
        int row = k * 256 + tid;
        float p = partial[0][row] + partial[1][row]
                + partial[2][row] + partial[3][row];
        part[(size_t)gf * B_SZ + rb + row] = p;
    }
}

// ---- final: 1 row/thread, sum 32 gf-partials + bias + sigmoid ----
__global__ __launch_bounds__(256)
void nam_final(const float* __restrict__ part, const float* __restrict__ bias,
               float* __restrict__ out)
{
    int b = blockIdx.x * 256 + threadIdx.x;
    float s = bias[0];
    #pragma unroll
    for (int gf = 0; gf < 32; ++gf)
        s += part[(size_t)gf * B_SZ + b];
    float p = 1.0f / (1.0f + __expf(-s));
    ((float2*)out)[b] = make_float2(1.0f - p, p);
}

extern "C" void kernel_launch(void* const* d_in, const int* in_sizes, int n_in,
                              void* d_out, int out_size, void* d_ws, size_t ws_size,
                              hipStream_t stream)
{
    const float* x    = (const float*)d_in[0];
    const float* w1   = (const float*)d_in[1];
    const float* b1   = (const float*)d_in[2];
    const float* w2   = (const float*)d_in[3];
    const float* b2   = (const float*)d_in[4];
    const float* w3   = (const float*)d_in[5];
    const float* b3   = (const float*)d_in[6];
    const float* bias = (const float*)d_in[7];
    float* out = (float*)d_out;

    unsigned short* ws = (unsigned short*)d_ws;
    float* part = (float*)(ws + WS_PART_SHORTS);

    nam_prep<<<dim3(256), dim3(256), 0, stream>>>(w2, ws);
    nam_main<<<dim3(2048), dim3(256), 0, stream>>>(
        x, w1, b1, b2, w3, b3, ws, part);
    nam_final<<<dim3(B_SZ / 256), dim3(256), 0, stream>>>(part, bias, out);
}

// Round 18
// 257.642 us; speedup vs baseline: 1.0356x; 1.0356x over previous
//
#include <hip/hip_runtime.h>
#include <hip/hip_bf16.h>

// NAM_89739046683406: per-feature tiny MLP (B=32768, F=128, H=64)
// logit(b) = bias + sum_f [ relu(relu(x[b,f]*w1[f]+b1[f]) @ w2[f] + b2[f]) . w3[f] + b3[f] ]
// out = [1-sigmoid, sigmoid]
//
// R18 = R16 (proven best: LB(256,3)/VGPR76/no-spill, grid 2048, gather+shfl x
// with prefetch, plain sole-writer stores) + ONE change: packed-f32 math
// (v_pk_fma_f32/v_pk_max_f32) for h1-gen and the relu.w3 epilogue.
// R17's lesson: b2-as-MFMA-C-operand (4 extra long-lived aligned quads) blew
// the aligned-tuple register budget -> 175MB scratch spill. Here register
// pressure is unchanged vs R16 (wk2/bk2/w3p reuse the same regs wk/bk/w3f
// held; acc[0:1]/acc[2:3] are already aligned pairs).

#define B_SZ 32768
#define F_SZ 128
#define H_SZ 64

typedef short short8 __attribute__((ext_vector_type(8)));   // bf16 x8
typedef float floatx4 __attribute__((ext_vector_type(4)));  // fp32 x4 acc
typedef float float2v __attribute__((ext_vector_type(2)));  // fp32 x2 (pk ops)

// round-half-up bf16 pair-pack (proven form)
__device__ __forceinline__ unsigned pkbf(float lo, float hi) {
    unsigned ua = __float_as_uint(lo) + 0x8000u;
    unsigned ub = __float_as_uint(hi) + 0x8000u;
    return (ua >> 16) | (ub & 0xFFFF0000u);
}

// ws layout (bytes): [0, 1MB) w2bf fragment table; [1MB, 5MB) part[32][32768]
#define WS_PART_SHORTS 524288

// ---- prep: pack w2 -> A-fragment order (grid-strided, uniform, 256 blocks)
// fragment layout: per f, unit idx = c*64+lane (c = gt*2+ks):
//   value = w2[f][k=(c&1)*32+(lane>>4)*8+j][g=(c>>1)*16+(lane&15)], j=0..7
__global__ __launch_bounds__(256)
void nam_prep(const float* __restrict__ w2, unsigned short* __restrict__ ws)
{
    int unit = blockIdx.x * 256 + threadIdx.x;   // 0..65535
    int f    = unit >> 9;             // 0..127
    int idx  = unit & 511;
    int c    = idx >> 6;
    int lane = idx & 63;
    int g    = (c >> 1) * 16 + (lane & 15);
    int k0   = (c & 1) * 32 + (lane >> 4) * 8;
    const float* w2f = w2 + (size_t)f * 4096;
    unsigned o0 = pkbf(w2f[(k0 + 0) * 64 + g], w2f[(k0 + 1) * 64 + g]);
    unsigned o1 = pkbf(w2f[(k0 + 2) * 64 + g], w2f[(k0 + 3) * 64 + g]);
    unsigned o2 = pkbf(w2f[(k0 + 4) * 64 + g], w2f[(k0 + 5) * 64 + g]);
    unsigned o3 = pkbf(w2f[(k0 + 6) * 64 + g], w2f[(k0 + 7) * 64 + g]);
    *(uint4*)((unsigned*)ws + ((size_t)f * 512 + idx) * 4) =
        make_uint4(o0, o1, o2, o3);
}

// ---- main: block = 4 waves; wave wv owns feature f = (bx>>6)*4+wv,
//      rows [rg*512, rg*512+512), rg = bx&63. 8 chunks of 64 rows.
//      Output: part[gf][rb..rb+512) plain store (sole writer).
__global__ __launch_bounds__(256, 3)
void nam_main(const float* __restrict__ x,
              const float* __restrict__ w1, const float* __restrict__ b1,
              const float* __restrict__ b2, const float* __restrict__ w3,
              const float* __restrict__ b3,
              const unsigned short* __restrict__ ws,
              float* __restrict__ part)
{
    __shared__ float partial[4][512];    // 8KB

    const int tid  = threadIdx.x;
    const int lane = tid & 63;
    const int wv   = tid >> 6;           // 0..3
    const int l15  = lane & 15;
    const int quad = lane >> 4;
    const int rg   = blockIdx.x & 63;
    const int gf   = blockIdx.x >> 6;    // 0..31
    const int f    = gf * 4 + wv;
    const int rb   = rg * 512;

    // ---- per-wave resident tables ----
    const short8* wp = (const short8*)ws + (size_t)f * 512 + lane;
    short8 wfrag[4][2];
    #pragma unroll
    for (int gt = 0; gt < 4; ++gt)
        #pragma unroll
        for (int ks = 0; ks < 2; ++ks)
            wfrag[gt][ks] = wp[(gt * 2 + ks) * 64];

    // w1/b1 fp32 as float2 pairs: k = ks*32 + quad*8 + 2t{,+1}
    float2v wk2[2][4], bk2[2][4];
    #pragma unroll
    for (int ks = 0; ks < 2; ++ks) {
        const float4* wq = (const float4*)(w1 + f * 64 + ks * 32 + quad * 8);
        const float4* bq = (const float4*)(b1 + f * 64 + ks * 32 + quad * 8);
        float4 wa = wq[0], wb = wq[1], ba = bq[0], bb = bq[1];
        wk2[ks][0] = float2v{wa.x, wa.y}; wk2[ks][1] = float2v{wa.z, wa.w};
        wk2[ks][2] = float2v{wb.x, wb.y}; wk2[ks][3] = float2v{wb.z, wb.w};
        bk2[ks][0] = float2v{ba.x, ba.y}; bk2[ks][1] = float2v{ba.z, ba.w};
        bk2[ks][2] = float2v{bb.x, bb.y}; bk2[ks][3] = float2v{bb.z, bb.w};
    }

    // b2 scalars (acc init movs, as in R16); w3 as float2 pairs
    float b2f[4][4];
    float2v w3p[4][2];
    #pragma unroll
    for (int gt = 0; gt < 4; ++gt) {
        float4 bv  = *(const float4*)(b2 + f * 64 + gt * 16 + quad * 4);
        float4 wv3 = *(const float4*)(w3 + f * 64 + gt * 16 + quad * 4);
        b2f[gt][0] = bv.x; b2f[gt][1] = bv.y; b2f[gt][2] = bv.z; b2f[gt][3] = bv.w;
        w3p[gt][0] = float2v{wv3.x, wv3.y};
        w3p[gt][1] = float2v{wv3.z, wv3.w};
    }
    const float b3f = b3[f];
    const float2v zero2 = float2v{0.0f, 0.0f};

    // ---- 8 chunks of 64 rows, software-pipelined x gather (R16 pattern) ----
    float xv = x[(size_t)(rb + lane) * F_SZ + f];   // chunk 0

    #pragma unroll 1
    for (int c = 0; c < 8; ++c) {
        float xvn;
        if (c < 7)
            xvn = x[(size_t)(rb + (c + 1) * 64 + lane) * F_SZ + f];

        float xf[4];
        #pragma unroll
        for (int bt = 0; bt < 4; ++bt)
            xf[bt] = __shfl(xv, bt * 16 + l15, 64);

        // h1 B-fragments: B[k=quad*8+j][n=bt*16+l15], packed-f32 math
        short8 hfrag[4][2];
        #pragma unroll
        for (int ks = 0; ks < 2; ++ks)
            #pragma unroll
            for (int bt = 0; bt < 4; ++bt) {
                float2v xbv = float2v{xf[bt], xf[bt]};
                union { short8 s8; __hip_bfloat162 h2[4]; } o;
                #pragma unroll
                for (int t = 0; t < 4; ++t) {
                    float2v h = __builtin_elementwise_fma(xbv, wk2[ks][t], bk2[ks][t]);
                    h = __builtin_elementwise_max(h, zero2);
                    o.h2[t] = __float22bfloat162_rn(make_float2(h.x, h.y));
                }
                hfrag[bt][ks] = o.s8;
            }

        // MFMA (acc init from b2f movs, R16 pattern) + packed epilogue
        // D layout: g = gt*16 + quad*4 + i, n = bt*16 + l15
        float2v s2[4] = {zero2, zero2, zero2, zero2};
        #pragma unroll
        for (int gt = 0; gt < 4; ++gt)
            #pragma unroll
            for (int bt = 0; bt < 4; ++bt) {
                floatx4 acc = {b2f[gt][0], b2f[gt][1], b2f[gt][2], b2f[gt][3]};
                acc = __builtin_amdgcn_mfma_f32_16x16x32_bf16(
                    wfrag[gt][0], hfrag[bt][0], acc, 0, 0, 0);
                acc = __builtin_amdgcn_mfma_f32_16x16x32_bf16(
                    wfrag[gt][1], hfrag[bt][1], acc, 0, 0, 0);
                float2v a01 = float2v{acc[0], acc[1]};
                float2v a23 = float2v{acc[2], acc[3]};
                s2[bt] = __builtin_elementwise_fma(
                    __builtin_elementwise_max(a01, zero2), w3p[gt][0], s2[bt]);
                s2[bt] = __builtin_elementwise_fma(
                    __builtin_elementwise_max(a23, zero2), w3p[gt][1], s2[bt]);
            }

        // horizontal + quad-reduce (row = bt*16 + l15), publish chunk rows
        #pragma unroll
        for (int bt = 0; bt < 4; ++bt) {
            float t = s2[bt].x + s2[bt].y;
            t += __shfl_xor(t, 16, 64);
            t += __shfl_xor(t, 32, 64);
            if (quad == 0)
                partial[wv][c * 64 + bt * 16 + l15] = t + b3f;
        }

        xv = xvn;
    }

    __syncthreads();

    // block reduce over the 4 features -> plain coalesced store (sole writer)
    #pragma unroll
    for (int k = 0; k < 2; ++k) {
        int row = k * 256 + tid;
        float p = partial[0][row] + partial[1][row]
                + partial[2][row] + partial[3][row];
        part[(size_t)gf * B_SZ + rb + row] = p;
    }
}

// ---- final: 1 row/thread, sum 32 gf-partials + bias + sigmoid ----
__global__ __launch_bounds__(256)
void nam_final(const float* __restrict__ part, const float* __restrict__ bias,
               float* __restrict__ out)
{
    int b = blockIdx.x * 256 + threadIdx.x;
    float s = bias[0];
    #pragma unroll
    for (int gf = 0; gf < 32; ++gf)
        s += part[(size_t)gf * B_SZ + b];
    float p = 1.0f / (1.0f + __expf(-s));
    ((float2*)out)[b] = make_float2(1.0f - p, p);
}

extern "C" void kernel_launch(void* const* d_in, const int* in_sizes, int n_in,
                              void* d_out, int out_size, void* d_ws, size_t ws_size,
                              hipStream_t stream)
{
    const float* x    = (const float*)d_in[0];
    const float* w1   = (const float*)d_in[1];
    const float* b1   = (const float*)d_in[2];
    const float* w2   = (const float*)d_in[3];
    const float* b2   = (const float*)d_in[4];
    const float* w3   = (const float*)d_in[5];
    const float* b3   = (const float*)d_in[6];
    const float* bias = (const float*)d_in[7];
    float* out = (float*)d_out;

    unsigned short* ws = (unsigned short*)d_ws;
    float* part = (float*)(ws + WS_PART_SHORTS);

    nam_prep<<<dim3(256), dim3(256), 0, stream>>>(w2, ws);
    nam_main<<<dim3(2048), dim3(256), 0, stream>>>(
        x, w1, b1, b2, w3, b3, ws, part);
    nam_final<<<dim3(B_SZ / 256), dim3(256), 0, stream>>>(part, bias, out);
}

// Round 19
// 126.462 us; speedup vs baseline: 2.1098x; 2.0373x over previous
//
#include <hip/hip_runtime.h>
#include <hip/hip_bf16.h>

// NAM_89739046683406: per-feature tiny MLP (B=32768, F=128, H=64)
// logit(b) = bias + sum_f [ relu(relu(x[b,f]*w1[f]+b1[f]) @ w2[f] + b2[f]) . w3[f] + b3[f] ]
// out = [1-sigmoid, sigmoid]
//
// R19 = R16 verbatim (session best: 125.5us total, main 57.8us).
// Proven configuration: f-outer, wave = 1 feature x 512 rows (8 chunks of 64),
// all per-f weights register-resident; LB(256,3) (VGPR 76, no scratch);
// grid 2048; gather+shfl x with software prefetch; plain sole-writer stores
// to part[32][B]; final kernel sums 32 partials + bias + sigmoid.
//
// Hard-won constraints (violating either costs 2-3x via scratch demotion,
// visible as FETCH/WRITE blowup while VGPR_Count stays low):
//   - LB must be (256,3): (256,4) demotes registers to scratch (R13-R15).
//   - NO float2v/ext-vector arrays with __builtin_elementwise_* math:
//     compiler demotes the arrays to scratch (R17/R18: 374MB FETCH).
//   - Judge spills by FETCH/WRITE counters, not VGPR_Count.

#define B_SZ 32768
#define F_SZ 128
#define H_SZ 64

typedef short short8 __attribute__((ext_vector_type(8)));   // bf16 x8
typedef float floatx4 __attribute__((ext_vector_type(4)));  // fp32 x4 acc

// round-half-up bf16 pair-pack (proven form)
__device__ __forceinline__ unsigned pkbf(float lo, float hi) {
    unsigned ua = __float_as_uint(lo) + 0x8000u;
    unsigned ub = __float_as_uint(hi) + 0x8000u;
    return (ua >> 16) | (ub & 0xFFFF0000u);
}

// ws layout (bytes): [0, 1MB) w2bf fragment table; [1MB, 5MB) part[32][32768]
#define WS_PART_SHORTS 524288

// ---- prep: pack w2 -> A-fragment order (grid-strided, uniform, 256 blocks)
// fragment layout: per f, unit idx = c*64+lane (c = gt*2+ks):
//   value = w2[f][k=(c&1)*32+(lane>>4)*8+j][g=(c>>1)*16+(lane&15)], j=0..7
__global__ __launch_bounds__(256)
void nam_prep(const float* __restrict__ w2, unsigned short* __restrict__ ws)
{
    int unit = blockIdx.x * 256 + threadIdx.x;   // 0..65535
    int f    = unit >> 9;             // 0..127
    int idx  = unit & 511;
    int c    = idx >> 6;
    int lane = idx & 63;
    int g    = (c >> 1) * 16 + (lane & 15);
    int k0   = (c & 1) * 32 + (lane >> 4) * 8;
    const float* w2f = w2 + (size_t)f * 4096;
    unsigned o0 = pkbf(w2f[(k0 + 0) * 64 + g], w2f[(k0 + 1) * 64 + g]);
    unsigned o1 = pkbf(w2f[(k0 + 2) * 64 + g], w2f[(k0 + 3) * 64 + g]);
    unsigned o2 = pkbf(w2f[(k0 + 4) * 64 + g], w2f[(k0 + 5) * 64 + g]);
    unsigned o3 = pkbf(w2f[(k0 + 6) * 64 + g], w2f[(k0 + 7) * 64 + g]);
    *(uint4*)((unsigned*)ws + ((size_t)f * 512 + idx) * 4) =
        make_uint4(o0, o1, o2, o3);
}

// ---- main: block = 4 waves; wave wv owns feature f = (bx>>6)*4+wv,
//      rows [rg*512, rg*512+512), rg = bx&63. 8 chunks of 64 rows.
//      Output: part[gf][rb..rb+512) plain store (sole writer).
__global__ __launch_bounds__(256, 3)
void nam_main(const float* __restrict__ x,
              const float* __restrict__ w1, const float* __restrict__ b1,
              const float* __restrict__ b2, const float* __restrict__ w3,
              const float* __restrict__ b3,
              const unsigned short* __restrict__ ws,
              float* __restrict__ part)
{
    __shared__ float partial[4][512];    // 8KB

    const int tid  = threadIdx.x;
    const int lane = tid & 63;
    const int wv   = tid >> 6;           // 0..3
    const int l15  = lane & 15;
    const int quad = lane >> 4;
    const int rg   = blockIdx.x & 63;
    const int gf   = blockIdx.x >> 6;    // 0..31
    const int f    = gf * 4 + wv;
    const int rb   = rg * 512;

    // ---- per-wave resident tables ----
    const short8* wp = (const short8*)ws + (size_t)f * 512 + lane;
    short8 wfrag[4][2];
    #pragma unroll
    for (int gt = 0; gt < 4; ++gt)
        #pragma unroll
        for (int ks = 0; ks < 2; ++ks)
            wfrag[gt][ks] = wp[(gt * 2 + ks) * 64];

    // w1/b1 fp32: element k = ks*32 + quad*8 + j
    float wk[2][8], bk[2][8];
    #pragma unroll
    for (int ks = 0; ks < 2; ++ks) {
        const float4* wq = (const float4*)(w1 + f * 64 + ks * 32 + quad * 8);
        const float4* bq = (const float4*)(b1 + f * 64 + ks * 32 + quad * 8);
        *(float4*)&wk[ks][0] = wq[0]; *(float4*)&wk[ks][4] = wq[1];
        *(float4*)&bk[ks][0] = bq[0]; *(float4*)&bk[ks][4] = bq[1];
    }

    // b2/w3 fp32: element g = gt*16 + quad*4 + i
    float b2f[4][4], w3f[4][4];
    #pragma unroll
    for (int gt = 0; gt < 4; ++gt) {
        *(float4*)&b2f[gt][0] = *(const float4*)(b2 + f * 64 + gt * 16 + quad * 4);
        *(float4*)&w3f[gt][0] = *(const float4*)(w3 + f * 64 + gt * 16 + quad * 4);
    }
    const float b3f = b3[f];

    // ---- 8 chunks of 64 rows, software-pipelined x gather ----
    float xv = x[(size_t)(rb + lane) * F_SZ + f];   // chunk 0

    #pragma unroll 1
    for (int c = 0; c < 8; ++c) {
        float xvn;
        if (c < 7)
            xvn = x[(size_t)(rb + (c + 1) * 64 + lane) * F_SZ + f];

        float xf[4];
        #pragma unroll
        for (int bt = 0; bt < 4; ++bt)
            xf[bt] = __shfl(xv, bt * 16 + l15, 64);

        // h1 B-fragments: B[k=quad*8+j][n=bt*16+l15]
        short8 hfrag[4][2];
        #pragma unroll
        for (int ks = 0; ks < 2; ++ks)
            #pragma unroll
            for (int bt = 0; bt < 4; ++bt) {
                union { short8 s8; __hip_bfloat162 h2[4]; } o;
                #pragma unroll
                for (int t = 0; t < 4; ++t) {
                    float h0 = fmaxf(fmaf(xf[bt], wk[ks][2 * t],     bk[ks][2 * t]),     0.0f);
                    float h1 = fmaxf(fmaf(xf[bt], wk[ks][2 * t + 1], bk[ks][2 * t + 1]), 0.0f);
                    o.h2[t] = __float22bfloat162_rn(make_float2(h0, h1));
                }
                hfrag[bt][ks] = o.s8;
            }

        // MFMA + epilogue; D layout: g = gt*16 + quad*4 + i, n = bt*16 + l15
        float t[4] = {0.0f, 0.0f, 0.0f, 0.0f};
        #pragma unroll
        for (int gt = 0; gt < 4; ++gt)
            #pragma unroll
            for (int bt = 0; bt < 4; ++bt) {
                floatx4 acc = {b2f[gt][0], b2f[gt][1], b2f[gt][2], b2f[gt][3]};
                acc = __builtin_amdgcn_mfma_f32_16x16x32_bf16(
                    wfrag[gt][0], hfrag[bt][0], acc, 0, 0, 0);
                acc = __builtin_amdgcn_mfma_f32_16x16x32_bf16(
                    wfrag[gt][1], hfrag[bt][1], acc, 0, 0, 0);
                #pragma unroll
                for (int i = 0; i < 4; ++i)
                    t[bt] = fmaf(fmaxf(acc[i], 0.0f), w3f[gt][i], t[bt]);
            }

        // quad-reduce (row = bt*16 + l15), publish per-chunk rows
        #pragma unroll
        for (int bt = 0; bt < 4; ++bt) {
            t[bt] += __shfl_xor(t[bt], 16, 64);
            t[bt] += __shfl_xor(t[bt], 32, 64);
        }
        if (quad == 0) {
            #pragma unroll
            for (int bt = 0; bt < 4; ++bt)
                partial[wv][c * 64 + bt * 16 + l15] = t[bt] + b3f;
        }

        xv = xvn;
    }

    __syncthreads();

    // block reduce over the 4 features -> plain coalesced store (sole writer)
    #pragma unroll
    for (int k = 0; k < 2; ++k) {
        int row = k * 256 + tid;
        float p = partial[0][row] + partial[1][row]
                + partial[2][row] + partial[3][row];
        part[(size_t)gf * B_SZ + rb + row] = p;
    }
}

// ---- final: 1 row/thread, sum 32 gf-partials + bias + sigmoid ----
__global__ __launch_bounds__(256)
void nam_final(const float* __restrict__ part, const float* __restrict__ bias,
               float* __restrict__ out)
{
    int b = blockIdx.x * 256 + threadIdx.x;
    float s = bias[0];
    #pragma unroll
    for (int gf = 0; gf < 32; ++gf)
        s += part[(size_t)gf * B_SZ + b];
    float p = 1.0f / (1.0f + __expf(-s));
    ((float2*)out)[b] = make_float2(1.0f - p, p);
}

extern "C" void kernel_launch(void* const* d_in, const int* in_sizes, int n_in,
                              void* d_out, int out_size, void* d_ws, size_t ws_size,
                              hipStream_t stream)
{
    const float* x    = (const float*)d_in[0];
    const float* w1   = (const float*)d_in[1];
    const float* b1   = (const float*)d_in[2];
    const float* w2   = (const float*)d_in[3];
    const float* b2   = (const float*)d_in[4];
    const float* w3   = (const float*)d_in[5];
    const float* b3   = (const float*)d_in[6];
    const float* bias = (const float*)d_in[7];
    float* out = (float*)d_out;

    unsigned short* ws = (unsigned short*)d_ws;
    float* part = (float*)(ws + WS_PART_SHORTS);

    nam_prep<<<dim3(256), dim3(256), 0, stream>>>(w2, ws);
    nam_main<<<dim3(2048), dim3(256), 0, stream>>>(
        x, w1, b1, b2, w3, b3, ws, part);
    nam_final<<<dim3(B_SZ / 256), dim3(256), 0, stream>>>(part, bias, out);
}

// Round 20
// 125.076 us; speedup vs baseline: 2.1332x; 1.0111x over previous
//
#include <hip/hip_runtime.h>
#include <hip/hip_bf16.h>

// NAM_89739046683406: per-feature tiny MLP (B=32768, F=128, H=64)
// logit(b) = bias + sum_f [ relu(relu(x[b,f]*w1[f]+b1[f]) @ w2[f] + b2[f]) . w3[f] + b3[f] ]
// out = [1-sigmoid, sigmoid]
//
// R20 = R19/R16 (proven: 126us total, main 57.4us, LB(256,3)/VGPR76/no-spill)
// + ONE isolated change: b2 held as floatx4 quads and fed DIRECTLY as the
// MFMA C operand (MFMA D!=C register semantics -> the 64 per-chunk acc-init
// v_movs vanish). R17 bundled this with the float2v-array packed math that
// R18 proved causes scratch demotion on its own, so b2-as-C never got a clean
// verdict. Register math: b2c[4] (16 aligned VGPRs) replaces b2f[4][4] (16
// scalar VGPRs) - net zero.
//
// Hard constraints (violations cost 2-3x via scratch demotion, visible as
// FETCH/WRITE blowup while VGPR_Count stays low):
//   - LB must be (256,3); (256,4) demotes (R13-R15).
//   - NO float2v/ext-vector arrays + __builtin_elementwise_* (R17/R18).
//   - Judge spills by FETCH/WRITE counters, not VGPR_Count.

#define B_SZ 32768
#define F_SZ 128
#define H_SZ 64

typedef short short8 __attribute__((ext_vector_type(8)));   // bf16 x8
typedef float floatx4 __attribute__((ext_vector_type(4)));  // fp32 x4 acc

// round-half-up bf16 pair-pack (proven form)
__device__ __forceinline__ unsigned pkbf(float lo, float hi) {
    unsigned ua = __float_as_uint(lo) + 0x8000u;
    unsigned ub = __float_as_uint(hi) + 0x8000u;
    return (ua >> 16) | (ub & 0xFFFF0000u);
}

// ws layout (bytes): [0, 1MB) w2bf fragment table; [1MB, 5MB) part[32][32768]
#define WS_PART_SHORTS 524288

// ---- prep: pack w2 -> A-fragment order (grid-strided, uniform, 256 blocks)
// fragment layout: per f, unit idx = c*64+lane (c = gt*2+ks):
//   value = w2[f][k=(c&1)*32+(lane>>4)*8+j][g=(c>>1)*16+(lane&15)], j=0..7
__global__ __launch_bounds__(256)
void nam_prep(const float* __restrict__ w2, unsigned short* __restrict__ ws)
{
    int unit = blockIdx.x * 256 + threadIdx.x;   // 0..65535
    int f    = unit >> 9;             // 0..127
    int idx  = unit & 511;
    int c    = idx >> 6;
    int lane = idx & 63;
    int g    = (c >> 1) * 16 + (lane & 15);
    int k0   = (c & 1) * 32 + (lane >> 4) * 8;
    const float* w2f = w2 + (size_t)f * 4096;
    unsigned o0 = pkbf(w2f[(k0 + 0) * 64 + g], w2f[(k0 + 1) * 64 + g]);
    unsigned o1 = pkbf(w2f[(k0 + 2) * 64 + g], w2f[(k0 + 3) * 64 + g]);
    unsigned o2 = pkbf(w2f[(k0 + 4) * 64 + g], w2f[(k0 + 5) * 64 + g]);
    unsigned o3 = pkbf(w2f[(k0 + 6) * 64 + g], w2f[(k0 + 7) * 64 + g]);
    *(uint4*)((unsigned*)ws + ((size_t)f * 512 + idx) * 4) =
        make_uint4(o0, o1, o2, o3);
}

// ---- main: block = 4 waves; wave wv owns feature f = (bx>>6)*4+wv,
//      rows [rg*512, rg*512+512), rg = bx&63. 8 chunks of 64 rows.
//      Output: part[gf][rb..rb+512) plain store (sole writer).
__global__ __launch_bounds__(256, 3)
void nam_main(const float* __restrict__ x,
              const float* __restrict__ w1, const float* __restrict__ b1,
              const float* __restrict__ b2, const float* __restrict__ w3,
              const float* __restrict__ b3,
              const unsigned short* __restrict__ ws,
              float* __restrict__ part)
{
    __shared__ float partial[4][512];    // 8KB

    const int tid  = threadIdx.x;
    const int lane = tid & 63;
    const int wv   = tid >> 6;           // 0..3
    const int l15  = lane & 15;
    const int quad = lane >> 4;
    const int rg   = blockIdx.x & 63;
    const int gf   = blockIdx.x >> 6;    // 0..31
    const int f    = gf * 4 + wv;
    const int rb   = rg * 512;

    // ---- per-wave resident tables ----
    const short8* wp = (const short8*)ws + (size_t)f * 512 + lane;
    short8 wfrag[4][2];
    #pragma unroll
    for (int gt = 0; gt < 4; ++gt)
        #pragma unroll
        for (int ks = 0; ks < 2; ++ks)
            wfrag[gt][ks] = wp[(gt * 2 + ks) * 64];

    // w1/b1 fp32: element k = ks*32 + quad*8 + j
    float wk[2][8], bk[2][8];
    #pragma unroll
    for (int ks = 0; ks < 2; ++ks) {
        const float4* wq = (const float4*)(w1 + f * 64 + ks * 32 + quad * 8);
        const float4* bq = (const float4*)(b1 + f * 64 + ks * 32 + quad * 8);
        *(float4*)&wk[ks][0] = wq[0]; *(float4*)&wk[ks][4] = wq[1];
        *(float4*)&bk[ks][0] = bq[0]; *(float4*)&bk[ks][4] = bq[1];
    }

    // b2 as MFMA C operand quads; w3 scalar: element g = gt*16 + quad*4 + i
    floatx4 b2c[4];
    float w3f[4][4];
    #pragma unroll
    for (int gt = 0; gt < 4; ++gt) {
        float4 bv  = *(const float4*)(b2 + f * 64 + gt * 16 + quad * 4);
        float4 wv3 = *(const float4*)(w3 + f * 64 + gt * 16 + quad * 4);
        b2c[gt] = floatx4{bv.x, bv.y, bv.z, bv.w};
        w3f[gt][0] = wv3.x; w3f[gt][1] = wv3.y;
        w3f[gt][2] = wv3.z; w3f[gt][3] = wv3.w;
    }
    const float b3f = b3[f];

    // ---- 8 chunks of 64 rows, software-pipelined x gather ----
    float xv = x[(size_t)(rb + lane) * F_SZ + f];   // chunk 0

    #pragma unroll 1
    for (int c = 0; c < 8; ++c) {
        float xvn;
        if (c < 7)
            xvn = x[(size_t)(rb + (c + 1) * 64 + lane) * F_SZ + f];

        float xf[4];
        #pragma unroll
        for (int bt = 0; bt < 4; ++bt)
            xf[bt] = __shfl(xv, bt * 16 + l15, 64);

        // h1 B-fragments: B[k=quad*8+j][n=bt*16+l15]
        short8 hfrag[4][2];
        #pragma unroll
        for (int ks = 0; ks < 2; ++ks)
            #pragma unroll
            for (int bt = 0; bt < 4; ++bt) {
                union { short8 s8; __hip_bfloat162 h2[4]; } o;
                #pragma unroll
                for (int t = 0; t < 4; ++t) {
                    float h0 = fmaxf(fmaf(xf[bt], wk[ks][2 * t],     bk[ks][2 * t]),     0.0f);
                    float h1 = fmaxf(fmaf(xf[bt], wk[ks][2 * t + 1], bk[ks][2 * t + 1]), 0.0f);
                    o.h2[t] = __float22bfloat162_rn(make_float2(h0, h1));
                }
                hfrag[bt][ks] = o.s8;
            }

        // MFMA (C = b2c direct, D != C) + epilogue
        // D layout: g = gt*16 + quad*4 + i, n = bt*16 + l15
        float t[4] = {0.0f, 0.0f, 0.0f, 0.0f};
        #pragma unroll
        for (int gt = 0; gt < 4; ++gt)
            #pragma unroll
            for (int bt = 0; bt < 4; ++bt) {
                floatx4 acc = __builtin_amdgcn_mfma_f32_16x16x32_bf16(
                    wfrag[gt][0], hfrag[bt][0], b2c[gt], 0, 0, 0);
                acc = __builtin_amdgcn_mfma_f32_16x16x32_bf16(
                    wfrag[gt][1], hfrag[bt][1], acc, 0, 0, 0);
                #pragma unroll
                for (int i = 0; i < 4; ++i)
                    t[bt] = fmaf(fmaxf(acc[i], 0.0f), w3f[gt][i], t[bt]);
            }

        // quad-reduce (row = bt*16 + l15), publish per-chunk rows
        #pragma unroll
        for (int bt = 0; bt < 4; ++bt) {
            t[bt] += __shfl_xor(t[bt], 16, 64);
            t[bt] += __shfl_xor(t[bt], 32, 64);
        }
        if (quad == 0) {
            #pragma unroll
            for (int bt = 0; bt < 4; ++bt)
                partial[wv][c * 64 + bt * 16 + l15] = t[bt] + b3f;
        }

        xv = xvn;
    }

    __syncthreads();

    // block reduce over the 4 features -> plain coalesced store (sole writer)
    #pragma unroll
    for (int k = 0; k < 2; ++k) {
        int row = k * 256 + tid;
        float p = partial[0][row] + partial[1][row]
                + partial[2][row] + partial[3][row];
        part[(size_t)gf * B_SZ + rb + row] = p;
    }
}

// ---- final: 1 row/thread, sum 32 gf-partials + bias + sigmoid ----
__global__ __launch_bounds__(256)
void nam_final(const float* __restrict__ part, const float* __restrict__ bias,
               float* __restrict__ out)
{
    int b = blockIdx.x * 256 + threadIdx.x;
    float s = bias[0];
    #pragma unroll
    for (int gf = 0; gf < 32; ++gf)
        s += part[(size_t)gf * B_SZ + b];
    float p = 1.0f / (1.0f + __expf(-s));
    ((float2*)out)[b] = make_float2(1.0f - p, p);
}

extern "C" void kernel_launch(void* const* d_in, const int* in_sizes, int n_in,
                              void* d_out, int out_size, void* d_ws, size_t ws_size,
                              hipStream_t stream)
{
    const float* x    = (const float*)d_in[0];
    const float* w1   = (const float*)d_in[1];
    const float* b1   = (const float*)d_in[2];
    const float* w2   = (const float*)d_in[3];
    const float* b2   = (const float*)d_in[4];
    const float* w3   = (const float*)d_in[5];
    const float* b3   = (const float*)d_in[6];
    const float* bias = (const float*)d_in[7];
    float* out = (float*)d_out;

    unsigned short* ws = (unsigned short*)d_ws;
    float* part = (float*)(ws + WS_PART_SHORTS);

    nam_prep<<<dim3(256), dim3(256), 0, stream>>>(w2, ws);
    nam_main<<<dim3(2048), dim3(256), 0, stream>>>(
        x, w1, b1, b2, w3, b3, ws, part);
    nam_final<<<dim3(B_SZ / 256), dim3(256), 0, stream>>>(part, bias, out);
}

// Round 21
// 123.932 us; speedup vs baseline: 2.1529x; 1.0092x over previous
//
#include <hip/hip_runtime.h>
#include <hip/hip_bf16.h>

// NAM_89739046683406: per-feature tiny MLP (B=32768, F=128, H=64)
// logit(b) = bias + sum_f [ relu(relu(x[b,f]*w1[f]+b1[f]) @ w2[f] + b2[f]) . w3[f] + b3[f] ]
// out = [1-sigmoid, sigmoid]
//
// R21 = R20 with the prep dispatch FUSED into nam_main: each wave packs its
// own f's w2 MFMA A-fragments directly from fp32 w2 in a preamble (identical
// pkbf bits to the old prep table; 64 scalar loads, quad-rows read 16
// contiguous g -> 4 lines/instr, L2-amortized over the 64 blocks per gf).
// 2 dispatches total. Tests whether the ~61us out-of-main time is dispatch
// boundaries (total -> ~112-118) or fixed harness overhead (neutral ~125).
//
// Hard constraints (violations cost 2-3x via scratch demotion, visible as
// FETCH/WRITE blowup while VGPR_Count stays low):
//   - LB must be (256,3); (256,4) demotes (R13-R15).
//   - NO float2v/ext-vector arrays + __builtin_elementwise_* (R17/R18).
//   - Judge spills by FETCH/WRITE counters, not VGPR_Count.

#define B_SZ 32768
#define F_SZ 128
#define H_SZ 64

typedef short short8 __attribute__((ext_vector_type(8)));   // bf16 x8
typedef float floatx4 __attribute__((ext_vector_type(4)));  // fp32 x4 acc

// round-half-up bf16 pair-pack (proven form)
__device__ __forceinline__ unsigned pkbf(float lo, float hi) {
    unsigned ua = __float_as_uint(lo) + 0x8000u;
    unsigned ub = __float_as_uint(hi) + 0x8000u;
    return (ua >> 16) | (ub & 0xFFFF0000u);
}

// ---- main: block = 4 waves; wave wv owns feature f = (bx>>6)*4+wv,
//      rows [rg*512, rg*512+512), rg = bx&63. 8 chunks of 64 rows.
//      Preamble packs w2[f] -> A-fragments in registers (no prep kernel).
//      Output: part[gf][rb..rb+512) plain store (sole writer).
__global__ __launch_bounds__(256, 3)
void nam_main(const float* __restrict__ x,
              const float* __restrict__ w1, const float* __restrict__ b1,
              const float* __restrict__ b2, const float* __restrict__ w3,
              const float* __restrict__ b3,
              const float* __restrict__ w2,
              float* __restrict__ part)
{
    __shared__ float partial[4][512];    // 8KB

    const int tid  = threadIdx.x;
    const int lane = tid & 63;
    const int wv   = tid >> 6;           // 0..3
    const int l15  = lane & 15;
    const int quad = lane >> 4;
    const int rg   = blockIdx.x & 63;
    const int gf   = blockIdx.x >> 6;    // 0..31
    const int f    = gf * 4 + wv;
    const int rb   = rg * 512;

    // ---- per-wave resident tables ----
    // w2 A-fragments packed in-place from fp32 source:
    // frag (gt,ks): elem j = w2[f][k=ks*32+quad*8+j][g=gt*16+l15]
    const float* w2f = w2 + (size_t)f * H_SZ * H_SZ;
    short8 wfrag[4][2];
    #pragma unroll
    for (int gt = 0; gt < 4; ++gt)
        #pragma unroll
        for (int ks = 0; ks < 2; ++ks) {
            const float* src = w2f + (ks * 32 + quad * 8) * H_SZ + gt * 16 + l15;
            union { short8 s8; unsigned u[4]; } o;
            #pragma unroll
            for (int t = 0; t < 4; ++t)
                o.u[t] = pkbf(src[(2 * t) * H_SZ], src[(2 * t + 1) * H_SZ]);
            wfrag[gt][ks] = o.s8;
        }

    // w1/b1 fp32: element k = ks*32 + quad*8 + j
    float wk[2][8], bk[2][8];
    #pragma unroll
    for (int ks = 0; ks < 2; ++ks) {
        const float4* wq = (const float4*)(w1 + f * 64 + ks * 32 + quad * 8);
        const float4* bq = (const float4*)(b1 + f * 64 + ks * 32 + quad * 8);
        *(float4*)&wk[ks][0] = wq[0]; *(float4*)&wk[ks][4] = wq[1];
        *(float4*)&bk[ks][0] = bq[0]; *(float4*)&bk[ks][4] = bq[1];
    }

    // b2 as MFMA C operand quads; w3 scalar: element g = gt*16 + quad*4 + i
    floatx4 b2c[4];
    float w3f[4][4];
    #pragma unroll
    for (int gt = 0; gt < 4; ++gt) {
        float4 bv  = *(const float4*)(b2 + f * 64 + gt * 16 + quad * 4);
        float4 wv3 = *(const float4*)(w3 + f * 64 + gt * 16 + quad * 4);
        b2c[gt] = floatx4{bv.x, bv.y, bv.z, bv.w};
        w3f[gt][0] = wv3.x; w3f[gt][1] = wv3.y;
        w3f[gt][2] = wv3.z; w3f[gt][3] = wv3.w;
    }
    const float b3f = b3[f];

    // ---- 8 chunks of 64 rows, software-pipelined x gather ----
    float xv = x[(size_t)(rb + lane) * F_SZ + f];   // chunk 0

    #pragma unroll 1
    for (int c = 0; c < 8; ++c) {
        float xvn;
        if (c < 7)
            xvn = x[(size_t)(rb + (c + 1) * 64 + lane) * F_SZ + f];

        float xf[4];
        #pragma unroll
        for (int bt = 0; bt < 4; ++bt)
            xf[bt] = __shfl(xv, bt * 16 + l15, 64);

        // h1 B-fragments: B[k=quad*8+j][n=bt*16+l15]
        short8 hfrag[4][2];
        #pragma unroll
        for (int ks = 0; ks < 2; ++ks)
            #pragma unroll
            for (int bt = 0; bt < 4; ++bt) {
                union { short8 s8; __hip_bfloat162 h2[4]; } o;
                #pragma unroll
                for (int t = 0; t < 4; ++t) {
                    float h0 = fmaxf(fmaf(xf[bt], wk[ks][2 * t],     bk[ks][2 * t]),     0.0f);
                    float h1 = fmaxf(fmaf(xf[bt], wk[ks][2 * t + 1], bk[ks][2 * t + 1]), 0.0f);
                    o.h2[t] = __float22bfloat162_rn(make_float2(h0, h1));
                }
                hfrag[bt][ks] = o.s8;
            }

        // MFMA (C = b2c direct, D != C) + epilogue
        // D layout: g = gt*16 + quad*4 + i, n = bt*16 + l15
        float t[4] = {0.0f, 0.0f, 0.0f, 0.0f};
        #pragma unroll
        for (int gt = 0; gt < 4; ++gt)
            #pragma unroll
            for (int bt = 0; bt < 4; ++bt) {
                floatx4 acc = __builtin_amdgcn_mfma_f32_16x16x32_bf16(
                    wfrag[gt][0], hfrag[bt][0], b2c[gt], 0, 0, 0);
                acc = __builtin_amdgcn_mfma_f32_16x16x32_bf16(
                    wfrag[gt][1], hfrag[bt][1], acc, 0, 0, 0);
                #pragma unroll
                for (int i = 0; i < 4; ++i)
                    t[bt] = fmaf(fmaxf(acc[i], 0.0f), w3f[gt][i], t[bt]);
            }

        // quad-reduce (row = bt*16 + l15), publish per-chunk rows
        #pragma unroll
        for (int bt = 0; bt < 4; ++bt) {
            t[bt] += __shfl_xor(t[bt], 16, 64);
            t[bt] += __shfl_xor(t[bt], 32, 64);
        }
        if (quad == 0) {
            #pragma unroll
            for (int bt = 0; bt < 4; ++bt)
                partial[wv][c * 64 + bt * 16 + l15] = t[bt] + b3f;
        }

        xv = xvn;
    }

    __syncthreads();

    // block reduce over the 4 features -> plain coalesced store (sole writer)
    #pragma unroll
    for (int k = 0; k < 2; ++k) {
        int row = k * 256 + tid;
        float p = partial[0][row] + partial[1][row]
                + partial[2][row] + partial[3][row];
        part[(size_t)gf * B_SZ + rb + row] = p;
    }
}

// ---- final: 1 row/thread, sum 32 gf-partials + bias + sigmoid ----
__global__ __launch_bounds__(256)
void nam_final(const float* __restrict__ part, const float* __restrict__ bias,
               float* __restrict__ out)
{
    int b = blockIdx.x * 256 + threadIdx.x;
    float s = bias[0];
    #pragma unroll
    for (int gf = 0; gf < 32; ++gf)
        s += part[(size_t)gf * B_SZ + b];
    float p = 1.0f / (1.0f + __expf(-s));
    ((float2*)out)[b] = make_float2(1.0f - p, p);
}

extern "C" void kernel_launch(void* const* d_in, const int* in_sizes, int n_in,
                              void* d_out, int out_size, void* d_ws, size_t ws_size,
                              hipStream_t stream)
{
    const float* x    = (const float*)d_in[0];
    const float* w1   = (const float*)d_in[1];
    const float* b1   = (const float*)d_in[2];
    const float* w2   = (const float*)d_in[3];
    const float* b2   = (const float*)d_in[4];
    const float* w3   = (const float*)d_in[5];
    const float* b3   = (const float*)d_in[6];
    const float* bias = (const float*)d_in[7];
    float* out = (float*)d_out;

    float* part = (float*)d_ws;   // part[32][B_SZ], 4MB

    nam_main<<<dim3(2048), dim3(256), 0, stream>>>(
        x, w1, b1, b2, w3, b3, w2, part);
    nam_final<<<dim3(B_SZ / 256), dim3(256), 0, stream>>>(part, bias, out);
}